// Round 5
// baseline (6810.638 us; speedup 1.0000x reference)
//
#include <hip/hip_runtime.h>

#define NB    1024
#define TSEQ  336
#define DIM   64
#define GATES 256
#define PRED  96
#define THREADS 512
#define ROWS  2          // batch rows per block; grid = NB/ROWS = 512 -> 2 blocks/CU

// LDS (float offsets). No weight matrices in LDS (R4: per-lane ds_read_b128 is
// ~8-way conflicted regardless of layout; weights live in VGPRs). All LDS ops
// are stride-1 b32 or wave-uniform b128 broadcasts (both conflict-free).
#define P0O   0        // layer-0 partials [4 copies][2 rows][256 gates] = 2048
#define P1O   2048     // layer-1 partials [4][2][256] = 2048
#define WFCO  4096     // W_fc [16][4][64] : (k4,c,j) = W[j][4k4+c] = 4096
#define H0O   8192     // [2][64]
#define H1O   8320     // [2][64]
#define DBO   8448     // [2][64] decoder feedback
#define BS0O  8576     // 256
#define BS1O  8832     // 256
#define BFCO  9088     // 64
#define SMF   9152
#define SMEM_BYTES (SMF * 4)   // 36.6 KB -> 2 blocks/CU fits in 160 KB

__device__ __forceinline__ float sigm(float v)  { return 1.0f / (1.0f + __expf(-v)); }
__device__ __forceinline__ float tanh_(float v) { return 1.0f - 2.0f / (__expf(2.0f * v) + 1.0f); }

__device__ __forceinline__ void fma4v(float& acc, const float4 xv, const float4 w) {
    acc = fmaf(xv.x, w.x, acc); acc = fmaf(xv.y, w.y, acc);
    acc = fmaf(xv.z, w.z, acc); acc = fmaf(xv.w, w.w, acc);
}

extern "C" __global__ void __launch_bounds__(THREADS, 4)   // 4 waves/EU -> 2 blocks/CU, VGPR<=128
rnn_fused(const float* __restrict__ x,
          const float* __restrict__ Wih0, const float* __restrict__ Whh0,
          const float* __restrict__ bih0, const float* __restrict__ bhh0,
          const float* __restrict__ Wih1, const float* __restrict__ Whh1,
          const float* __restrict__ bih1, const float* __restrict__ bhh1,
          const float* __restrict__ Wfc,  const float* __restrict__ bfc,
          float* __restrict__ out)
{
    extern __shared__ float sm[];
    const int tid = threadIdx.x;
    const int bid = blockIdx.x;
    const int grp = tid >> 7;          // 0..3 (wave-uniform): partial-copy index
    const int m   = grp & 1;           // 0: ih matrix, 1: hh matrix
    const int kh  = grp >> 1;          // k-half
    const int gp  = tid & 127;
    const int g0  = gp, g1 = gp + 128; // owned gate rows
    const int pb  = grp * 512;         // partial base: [copy][row][gate]

    // combine roles (disjoint wave sets):
    //   combine0: tid in [0,128)    -> (rc0, jc0)
    //   combine1: tid in [256,384)  -> (rc1, jc1)
    const int rc0 = (tid & 127) >> 6, jc0 = tid & 63;
    const int rc1 = rc0,              jc1 = jc0;     // same formulas, different threads

    // ---- prologue staging ----
    if (tid < GATES) {
        sm[BS0O + tid] = bih0[tid] + bhh0[tid];
        sm[BS1O + tid] = bih1[tid] + bhh1[tid];
    }
    if (tid < DIM) sm[BFCO + tid] = bfc[tid];
    if (tid < 2 * DIM) { sm[H0O + tid] = 0.0f; sm[H1O + tid] = 0.0f; }
    for (int idx = tid; idx < DIM * DIM; idx += THREADS) {   // W_fc: (k4,c,j)
        const int j = idx >> 6, k = idx & 63;
        sm[WFCO + (k >> 2) * 256 + (k & 3) * 64 + j] = Wfc[idx];
    }

    // ---- recurrent weights in registers: 32 float4 = 128 VGPR ----
    const float* Wsrc0 = m ? Whh0 : Wih0;
    const float* Wsrc1 = m ? Whh1 : Wih1;
    float4 w0a[8], w0b[8], w1a[8], w1b[8];
#pragma unroll
    for (int k4 = 0; k4 < 8; ++k4) {
        w0a[k4] = *reinterpret_cast<const float4*>(Wsrc0 + g0 * DIM + kh * 32 + k4 * 4);
        w0b[k4] = *reinterpret_cast<const float4*>(Wsrc0 + g1 * DIM + kh * 32 + k4 * 4);
        w1a[k4] = *reinterpret_cast<const float4*>(Wsrc1 + g0 * DIM + kh * 32 + k4 * 4);
        w1b[k4] = *reinterpret_cast<const float4*>(Wsrc1 + g1 * DIM + kh * 32 + k4 * 4);
    }
    __syncthreads();

    const int row0 = bid * ROWS;
    const float* xr0 = x + (size_t)(row0 + 0) * TSEQ * DIM + kh * 32;
    const float* xr1 = x + (size_t)(row0 + 1) * TSEQ * DIM + kh * 32;

    float c_state = 0.0f;   // c0 for tid<128; c1 for tid in [256,384)

    // ============ encoder: 336 steps, 3 barriers (combine1_{s-1} overlaps seg1) ============
    for (int s = 0; s < TSEQ; ++s) {
        // ---- seg1: layer-0 matvec (all) + combine1(s-1) on [256,384) ----
        if (s != 0 && tid >= 256 && tid < 384) {
            float pi = sm[BS1O + jc1],       pf = sm[BS1O + 64 + jc1];
            float pg = sm[BS1O + 128 + jc1], po = sm[BS1O + 192 + jc1];
#pragma unroll
            for (int cp = 0; cp < 4; ++cp) {
                const float* p = sm + P1O + cp * 512 + rc1 * 256;
                pi += p[jc1]; pf += p[64 + jc1]; pg += p[128 + jc1]; po += p[192 + jc1];
            }
            const float ig = sigm(pi), fg = sigm(pf), gg = tanh_(pg), og = sigm(po);
            c_state = fmaf(fg, c_state, ig * gg);
            sm[H1O + rc1 * 64 + jc1] = og * tanh_(c_state);
        }
        {
            float a00 = 0.0f, a01 = 0.0f, a10 = 0.0f, a11 = 0.0f;
            if (m == 0) {        // x-part: wave-uniform global loads (VMEM pipe)
                const int so = s * DIM;
#pragma unroll
                for (int k4 = 0; k4 < 8; ++k4) {
                    const float4 v0 = *reinterpret_cast<const float4*>(xr0 + so + k4 * 4);
                    const float4 v1 = *reinterpret_cast<const float4*>(xr1 + so + k4 * 4);
                    fma4v(a00, v0, w0a[k4]); fma4v(a01, v0, w0b[k4]);
                    fma4v(a10, v1, w0a[k4]); fma4v(a11, v1, w0b[k4]);
                }
            } else {             // h-part: wave-uniform LDS b128 broadcasts (free)
#pragma unroll
                for (int k4 = 0; k4 < 8; ++k4) {
                    const float4 v0 = *reinterpret_cast<const float4*>(sm + H0O + 0 * 64 + kh * 32 + k4 * 4);
                    const float4 v1 = *reinterpret_cast<const float4*>(sm + H0O + 1 * 64 + kh * 32 + k4 * 4);
                    fma4v(a00, v0, w0a[k4]); fma4v(a01, v0, w0b[k4]);
                    fma4v(a10, v1, w0a[k4]); fma4v(a11, v1, w0b[k4]);
                }
            }
            sm[P0O + pb + g0]       = a00; sm[P0O + pb + g1]       = a01;
            sm[P0O + pb + 256 + g0] = a10; sm[P0O + pb + 256 + g1] = a11;
        }
        __syncthreads();

        // ---- seg2: combine0 on tid<128 ----
        if (tid < 128) {
            float pi = sm[BS0O + jc0],       pf = sm[BS0O + 64 + jc0];
            float pg = sm[BS0O + 128 + jc0], po = sm[BS0O + 192 + jc0];
#pragma unroll
            for (int cp = 0; cp < 4; ++cp) {
                const float* p = sm + P0O + cp * 512 + rc0 * 256;
                pi += p[jc0]; pf += p[64 + jc0]; pg += p[128 + jc0]; po += p[192 + jc0];
            }
            const float ig = sigm(pi), fg = sigm(pf), gg = tanh_(pg), og = sigm(po);
            c_state = fmaf(fg, c_state, ig * gg);
            sm[H0O + tid] = og * tanh_(c_state);
        }
        __syncthreads();

        // ---- seg3: layer-1 matvec (m selects h0_s / h1_{s-1}) ----
        {
            const int ib = m ? H1O : H0O;
            float a00 = 0.0f, a01 = 0.0f, a10 = 0.0f, a11 = 0.0f;
#pragma unroll
            for (int k4 = 0; k4 < 8; ++k4) {
                const float4 v0 = *reinterpret_cast<const float4*>(sm + ib + 0 * 64 + kh * 32 + k4 * 4);
                const float4 v1 = *reinterpret_cast<const float4*>(sm + ib + 1 * 64 + kh * 32 + k4 * 4);
                fma4v(a00, v0, w1a[k4]); fma4v(a01, v0, w1b[k4]);
                fma4v(a10, v1, w1a[k4]); fma4v(a11, v1, w1b[k4]);
            }
            sm[P1O + pb + g0]       = a00; sm[P1O + pb + g1]       = a01;
            sm[P1O + pb + 256 + g0] = a10; sm[P1O + pb + 256 + g1] = a11;
        }
        __syncthreads();
    }

    // ---- final combine1 (s=335) -> decoder carry ----
    if (tid >= 256 && tid < 384) {
        float pi = sm[BS1O + jc1],       pf = sm[BS1O + 64 + jc1];
        float pg = sm[BS1O + 128 + jc1], po = sm[BS1O + 192 + jc1];
#pragma unroll
        for (int cp = 0; cp < 4; ++cp) {
            const float* p = sm + P1O + cp * 512 + rc1 * 256;
            pi += p[jc1]; pf += p[64 + jc1]; pg += p[128 + jc1]; po += p[192 + jc1];
        }
        const float ig = sigm(pi), fg = sigm(pf), gg = tanh_(pg), og = sigm(po);
        c_state = fmaf(fg, c_state, ig * gg);
        sm[DBO + rc1 * 64 + jc1] = og * tanh_(c_state);
    }
    __syncthreads();

    const float bfc_j = sm[BFCO + jc0];

    // ============ decoder: 96 autoregressive steps (zero-state cells) ============
    for (int p = 0; p < PRED; ++p) {
        // ---- cell0 matvec: m==0 groups (copies 0,2) from DBO ----
        if (m == 0) {
            float a00 = 0.0f, a01 = 0.0f, a10 = 0.0f, a11 = 0.0f;
#pragma unroll
            for (int k4 = 0; k4 < 8; ++k4) {
                const float4 v0 = *reinterpret_cast<const float4*>(sm + DBO + 0 * 64 + kh * 32 + k4 * 4);
                const float4 v1 = *reinterpret_cast<const float4*>(sm + DBO + 1 * 64 + kh * 32 + k4 * 4);
                fma4v(a00, v0, w0a[k4]); fma4v(a01, v0, w0b[k4]);
                fma4v(a10, v1, w0a[k4]); fma4v(a11, v1, w0b[k4]);
            }
            sm[P0O + pb + g0]       = a00; sm[P0O + pb + g1]       = a01;
            sm[P0O + pb + 256 + g0] = a10; sm[P0O + pb + 256 + g1] = a11;
        }
        __syncthreads();
        if (tid < 128) {   // combine0 zero-state: c = i*g
            float pi = sm[BS0O + jc0], pg = sm[BS0O + 128 + jc0], po = sm[BS0O + 192 + jc0];
            const float* pA = sm + P0O + 0 * 512 + rc0 * 256;
            const float* pB = sm + P0O + 2 * 512 + rc0 * 256;
            pi += pA[jc0] + pB[jc0];
            pg += pA[128 + jc0] + pB[128 + jc0];
            po += pA[192 + jc0] + pB[192 + jc0];
            const float ig = sigm(pi), gg = tanh_(pg), og = sigm(po);
            sm[H0O + tid] = og * tanh_(ig * gg);
        }
        __syncthreads();

        // ---- cell1 matvec: m==0 groups from H0 ----
        if (m == 0) {
            float a00 = 0.0f, a01 = 0.0f, a10 = 0.0f, a11 = 0.0f;
#pragma unroll
            for (int k4 = 0; k4 < 8; ++k4) {
                const float4 v0 = *reinterpret_cast<const float4*>(sm + H0O + 0 * 64 + kh * 32 + k4 * 4);
                const float4 v1 = *reinterpret_cast<const float4*>(sm + H0O + 1 * 64 + kh * 32 + k4 * 4);
                fma4v(a00, v0, w1a[k4]); fma4v(a01, v0, w1b[k4]);
                fma4v(a10, v1, w1a[k4]); fma4v(a11, v1, w1b[k4]);
            }
            sm[P1O + pb + g0]       = a00; sm[P1O + pb + g1]       = a01;
            sm[P1O + pb + 256 + g0] = a10; sm[P1O + pb + 256 + g1] = a11;
        }
        __syncthreads();
        if (tid >= 256 && tid < 384) {  // combine1 zero-state
            float pi = sm[BS1O + jc1], pg = sm[BS1O + 128 + jc1], po = sm[BS1O + 192 + jc1];
            const float* pA = sm + P1O + 0 * 512 + rc1 * 256;
            const float* pB = sm + P1O + 2 * 512 + rc1 * 256;
            pi += pA[jc1] + pB[jc1];
            pg += pA[128 + jc1] + pB[128 + jc1];
            po += pA[192 + jc1] + pB[192 + jc1];
            const float ig = sigm(pi), gg = tanh_(pg), og = sigm(po);
            sm[H1O + rc1 * 64 + jc1] = og * tanh_(ig * gg);
        }
        __syncthreads();

        // ---- FC (tid<128): uniform h1 b128 + stride-1 b32 W_fc ----
        if (tid < 128) {
            float acc = bfc_j;
            const float4* hp = reinterpret_cast<const float4*>(sm + H1O + rc0 * 64);
#pragma unroll
            for (int k4 = 0; k4 < 16; ++k4) {
                const float4 hv = hp[k4];
                const float* wp = sm + WFCO + k4 * 256;
                acc = fmaf(hv.x, wp[jc0],       acc);
                acc = fmaf(hv.y, wp[64 + jc0],  acc);
                acc = fmaf(hv.z, wp[128 + jc0], acc);
                acc = fmaf(hv.w, wp[192 + jc0], acc);
            }
            out[(size_t)(row0 + rc0) * PRED * DIM + p * DIM + jc0] = acc;
            sm[DBO + tid] = acc;
        }
        __syncthreads();
    }
}

extern "C" void kernel_launch(void* const* d_in, const int* in_sizes, int n_in,
                              void* d_out, int out_size, void* d_ws, size_t ws_size,
                              hipStream_t stream) {
    const float* x    = (const float*)d_in[0];
    const float* Wih0 = (const float*)d_in[1];
    const float* Whh0 = (const float*)d_in[2];
    const float* bih0 = (const float*)d_in[3];
    const float* bhh0 = (const float*)d_in[4];
    const float* Wih1 = (const float*)d_in[5];
    const float* Whh1 = (const float*)d_in[6];
    const float* bih1 = (const float*)d_in[7];
    const float* bhh1 = (const float*)d_in[8];
    const float* Wfc  = (const float*)d_in[9];
    const float* bfc  = (const float*)d_in[10];
    float* out = (float*)d_out;

    hipLaunchKernelGGL(rnn_fused, dim3(NB / ROWS), dim3(THREADS), SMEM_BYTES, stream,
                       x, Wih0, Whh0, bih0, bhh0, Wih1, Whh1, bih1, bhh1, Wfc, bfc, out);
}

// Round 6
// 3183.896 us; speedup vs baseline: 2.1391x; 2.1391x over previous
//
#include <hip/hip_runtime.h>

#define NB    1024
#define TSEQ  336
#define DIM   64
#define GATES 256
#define PRED  96
#define THREADS 1024
#define ROWS  4          // grid = NB/ROWS = 256 blocks, 1 block/CU, 16 waves (4/SIMD)

// LDS (float offsets), 87 KB. No weights in LDS (per-lane ds_read_b128 is
// ~8-way conflicted on gfx950 — R3; weights in VGPRs — R4). 8 partial copies
// (m x k-quarter). All LDS ops: stride-1 b32 or wave-uniform b128 broadcasts.
#define P0O   0        // layer-0 partials [8 copies][4 rows][256] = 8192
#define P1O   8192     // layer-1 partials [8][4][256] = 8192
#define WFCO  16384    // W_fc [16][4][64] : (k4,c,j) = W[j][4k4+c]
#define H0O   20480    // [4][64]
#define H1O   20736    // [4][64]
#define DBO   20992    // [4][64] decoder feedback
#define BS0O  21248    // 256
#define BS1O  21504    // 256
#define BFCO  21760    // 64
#define SMF   21824
#define SMEM_BYTES (SMF * 4)   // 87296 B -> needs dynamic-LDS opt-in

__device__ __forceinline__ float sigm(float v)  { return 1.0f / (1.0f + __expf(-v)); }
__device__ __forceinline__ float tanh_(float v) { return 1.0f - 2.0f / (__expf(2.0f * v) + 1.0f); }

__device__ __forceinline__ void fma4v(float& acc, const float4 xv, const float4 w) {
    acc = fmaf(xv.x, w.x, acc); acc = fmaf(xv.y, w.y, acc);
    acc = fmaf(xv.z, w.z, acc); acc = fmaf(xv.w, w.w, acc);
}

extern "C" __global__ void __launch_bounds__(THREADS, 4)   // 4 waves/EU, VGPR cap 128
rnn_fused(const float* __restrict__ x,
          const float* __restrict__ Wih0, const float* __restrict__ Whh0,
          const float* __restrict__ bih0, const float* __restrict__ bhh0,
          const float* __restrict__ Wih1, const float* __restrict__ Whh1,
          const float* __restrict__ bih1, const float* __restrict__ bhh1,
          const float* __restrict__ Wfc,  const float* __restrict__ bfc,
          float* __restrict__ out)
{
    extern __shared__ float sm[];
    const int tid = threadIdx.x;
    const int bid = blockIdx.x;
    const int grp = tid >> 7;          // 0..7 (wave-pair-uniform): partial-copy index
    const int m   = grp >> 2;          // grps 0-3: ih matrices; grps 4-7: hh matrices
    const int kq  = grp & 3;           // k-quarter
    const int ko  = kq * 16;           // k offset (floats)
    const int gp  = tid & 127;
    const int g0  = gp, g1 = gp + 128; // owned gate rows
    const int pb  = grp * 1024;        // partial base [copy][row][gate]

    // combine roles: combine0 = tid<256 (c0), combine1 = tid>=768 (c1); disjoint.
    const int rc = (tid & 255) >> 6;   // row   (works for both ranges)
    const int jc = tid & 63;           // hidden index

    // ---- prologue staging ----
    if (tid < GATES) {
        sm[BS0O + tid] = bih0[tid] + bhh0[tid];
        sm[BS1O + tid] = bih1[tid] + bhh1[tid];
    }
    if (tid < DIM) sm[BFCO + tid] = bfc[tid];
    if (tid < 256) { sm[H0O + tid] = 0.0f; sm[H1O + tid] = 0.0f; }
    for (int idx = tid; idx < DIM * DIM; idx += THREADS) {   // W_fc: (k4,c,j)
        const int j = idx >> 6, k = idx & 63;
        sm[WFCO + (k >> 2) * 256 + (k & 3) * 64 + j] = Wfc[idx];
    }

    // ---- weights in registers: 16 float4 = 64 VGPR (2 gates x 16 k x 2 layers) ----
    const float* Ws0 = m ? Whh0 : Wih0;
    const float* Ws1 = m ? Whh1 : Wih1;
    float4 w0a[4], w0b[4], w1a[4], w1b[4];
#pragma unroll
    for (int k4 = 0; k4 < 4; ++k4) {
        w0a[k4] = *reinterpret_cast<const float4*>(Ws0 + g0 * DIM + ko + k4 * 4);
        w0b[k4] = *reinterpret_cast<const float4*>(Ws0 + g1 * DIM + ko + k4 * 4);
        w1a[k4] = *reinterpret_cast<const float4*>(Ws1 + g0 * DIM + ko + k4 * 4);
        w1b[k4] = *reinterpret_cast<const float4*>(Ws1 + g1 * DIM + ko + k4 * 4);
    }
    __syncthreads();

    const int row0 = bid * ROWS;
    const float* xb = x + (size_t)row0 * TSEQ * DIM + ko;
    const size_t XRS = (size_t)TSEQ * DIM;   // x row stride

    float c_state = 0.0f;   // c0 for tid<256; c1 for tid>=768

    // ============ encoder: 336 steps, 3 barriers (combine1_{s-1} overlaps seg1) ============
    for (int s = 0; s < TSEQ; ++s) {
        // ---- seg1: combine1(s-1) on tid>=768 (m=1 waves), + layer-0 matvec all ----
        if (s != 0 && tid >= 768) {
            float pi = sm[BS1O + jc],       pf = sm[BS1O + 64 + jc];
            float pg = sm[BS1O + 128 + jc], po = sm[BS1O + 192 + jc];
#pragma unroll
            for (int cp = 0; cp < 8; ++cp) {
                const float* p = sm + P1O + cp * 1024 + rc * 256;
                pi += p[jc]; pf += p[64 + jc]; pg += p[128 + jc]; po += p[192 + jc];
            }
            const float ig = sigm(pi), fg = sigm(pf), gg = tanh_(pg), og = sigm(po);
            c_state = fmaf(fg, c_state, ig * gg);
            sm[H1O + rc * 64 + jc] = og * tanh_(c_state);
        }
        {
            float a0=0.f,a1=0.f,a2=0.f,a3=0.f,a4=0.f,a5=0.f,a6=0.f,a7=0.f;
            if (m == 0) {        // x-part: global loads (VMEM pipe, L2-resident stream)
                const float* xs = xb + (size_t)s * DIM;
#pragma unroll
                for (int k4 = 0; k4 < 4; ++k4) {
                    const float4 v0 = *reinterpret_cast<const float4*>(xs + 0 * XRS + k4 * 4);
                    const float4 v1 = *reinterpret_cast<const float4*>(xs + 1 * XRS + k4 * 4);
                    fma4v(a0, v0, w0a[k4]); fma4v(a1, v0, w0b[k4]);
                    fma4v(a2, v1, w0a[k4]); fma4v(a3, v1, w0b[k4]);
                    const float4 v2 = *reinterpret_cast<const float4*>(xs + 2 * XRS + k4 * 4);
                    const float4 v3 = *reinterpret_cast<const float4*>(xs + 3 * XRS + k4 * 4);
                    fma4v(a4, v2, w0a[k4]); fma4v(a5, v2, w0b[k4]);
                    fma4v(a6, v3, w0a[k4]); fma4v(a7, v3, w0b[k4]);
                }
            } else {             // h-part: wave-uniform LDS b128 broadcasts (free)
#pragma unroll
                for (int k4 = 0; k4 < 4; ++k4) {
                    const float4 v0 = *reinterpret_cast<const float4*>(sm + H0O + 0 * 64 + ko + k4 * 4);
                    const float4 v1 = *reinterpret_cast<const float4*>(sm + H0O + 1 * 64 + ko + k4 * 4);
                    fma4v(a0, v0, w0a[k4]); fma4v(a1, v0, w0b[k4]);
                    fma4v(a2, v1, w0a[k4]); fma4v(a3, v1, w0b[k4]);
                    const float4 v2 = *reinterpret_cast<const float4*>(sm + H0O + 2 * 64 + ko + k4 * 4);
                    const float4 v3 = *reinterpret_cast<const float4*>(sm + H0O + 3 * 64 + ko + k4 * 4);
                    fma4v(a4, v2, w0a[k4]); fma4v(a5, v2, w0b[k4]);
                    fma4v(a6, v3, w0a[k4]); fma4v(a7, v3, w0b[k4]);
                }
            }
            sm[P0O + pb + 0 * 256 + g0] = a0; sm[P0O + pb + 0 * 256 + g1] = a1;
            sm[P0O + pb + 1 * 256 + g0] = a2; sm[P0O + pb + 1 * 256 + g1] = a3;
            sm[P0O + pb + 2 * 256 + g0] = a4; sm[P0O + pb + 2 * 256 + g1] = a5;
            sm[P0O + pb + 3 * 256 + g0] = a6; sm[P0O + pb + 3 * 256 + g1] = a7;
        }
        __syncthreads();

        // ---- seg2: combine0 on tid<256 ----
        if (tid < 256) {
            float pi = sm[BS0O + jc],       pf = sm[BS0O + 64 + jc];
            float pg = sm[BS0O + 128 + jc], po = sm[BS0O + 192 + jc];
#pragma unroll
            for (int cp = 0; cp < 8; ++cp) {
                const float* p = sm + P0O + cp * 1024 + rc * 256;
                pi += p[jc]; pf += p[64 + jc]; pg += p[128 + jc]; po += p[192 + jc];
            }
            const float ig = sigm(pi), fg = sigm(pf), gg = tanh_(pg), og = sigm(po);
            c_state = fmaf(fg, c_state, ig * gg);
            sm[H0O + tid] = og * tanh_(c_state);
        }
        __syncthreads();

        // ---- seg3: layer-1 matvec (m selects h0_s / h1_{s-1}) ----
        {
            const int ib = m ? H1O : H0O;
            float a0=0.f,a1=0.f,a2=0.f,a3=0.f,a4=0.f,a5=0.f,a6=0.f,a7=0.f;
#pragma unroll
            for (int k4 = 0; k4 < 4; ++k4) {
                const float4 v0 = *reinterpret_cast<const float4*>(sm + ib + 0 * 64 + ko + k4 * 4);
                const float4 v1 = *reinterpret_cast<const float4*>(sm + ib + 1 * 64 + ko + k4 * 4);
                fma4v(a0, v0, w1a[k4]); fma4v(a1, v0, w1b[k4]);
                fma4v(a2, v1, w1a[k4]); fma4v(a3, v1, w1b[k4]);
                const float4 v2 = *reinterpret_cast<const float4*>(sm + ib + 2 * 64 + ko + k4 * 4);
                const float4 v3 = *reinterpret_cast<const float4*>(sm + ib + 3 * 64 + ko + k4 * 4);
                fma4v(a4, v2, w1a[k4]); fma4v(a5, v2, w1b[k4]);
                fma4v(a6, v3, w1a[k4]); fma4v(a7, v3, w1b[k4]);
            }
            sm[P1O + pb + 0 * 256 + g0] = a0; sm[P1O + pb + 0 * 256 + g1] = a1;
            sm[P1O + pb + 1 * 256 + g0] = a2; sm[P1O + pb + 1 * 256 + g1] = a3;
            sm[P1O + pb + 2 * 256 + g0] = a4; sm[P1O + pb + 2 * 256 + g1] = a5;
            sm[P1O + pb + 3 * 256 + g0] = a6; sm[P1O + pb + 3 * 256 + g1] = a7;
        }
        __syncthreads();
    }

    // ---- final combine1 (s=335) -> decoder carry ----
    if (tid >= 768) {
        float pi = sm[BS1O + jc],       pf = sm[BS1O + 64 + jc];
        float pg = sm[BS1O + 128 + jc], po = sm[BS1O + 192 + jc];
#pragma unroll
        for (int cp = 0; cp < 8; ++cp) {
            const float* p = sm + P1O + cp * 1024 + rc * 256;
            pi += p[jc]; pf += p[64 + jc]; pg += p[128 + jc]; po += p[192 + jc];
        }
        const float ig = sigm(pi), fg = sigm(pf), gg = tanh_(pg), og = sigm(po);
        c_state = fmaf(fg, c_state, ig * gg);
        sm[DBO + rc * 64 + jc] = og * tanh_(c_state);
    }
    __syncthreads();

    const float bfc_j = sm[BFCO + jc];

    // ============ decoder: 96 autoregressive steps (zero-state cells) ============
    for (int p = 0; p < PRED; ++p) {
        // ---- cell0 matvec: m==0 grps (copies 0..3) from DBO ----
        if (m == 0) {
            float a0=0.f,a1=0.f,a2=0.f,a3=0.f,a4=0.f,a5=0.f,a6=0.f,a7=0.f;
#pragma unroll
            for (int k4 = 0; k4 < 4; ++k4) {
                const float4 v0 = *reinterpret_cast<const float4*>(sm + DBO + 0 * 64 + ko + k4 * 4);
                const float4 v1 = *reinterpret_cast<const float4*>(sm + DBO + 1 * 64 + ko + k4 * 4);
                fma4v(a0, v0, w0a[k4]); fma4v(a1, v0, w0b[k4]);
                fma4v(a2, v1, w0a[k4]); fma4v(a3, v1, w0b[k4]);
                const float4 v2 = *reinterpret_cast<const float4*>(sm + DBO + 2 * 64 + ko + k4 * 4);
                const float4 v3 = *reinterpret_cast<const float4*>(sm + DBO + 3 * 64 + ko + k4 * 4);
                fma4v(a4, v2, w0a[k4]); fma4v(a5, v2, w0b[k4]);
                fma4v(a6, v3, w0a[k4]); fma4v(a7, v3, w0b[k4]);
            }
            sm[P0O + pb + 0 * 256 + g0] = a0; sm[P0O + pb + 0 * 256 + g1] = a1;
            sm[P0O + pb + 1 * 256 + g0] = a2; sm[P0O + pb + 1 * 256 + g1] = a3;
            sm[P0O + pb + 2 * 256 + g0] = a4; sm[P0O + pb + 2 * 256 + g1] = a5;
            sm[P0O + pb + 3 * 256 + g0] = a6; sm[P0O + pb + 3 * 256 + g1] = a7;
        }
        __syncthreads();
        if (tid < 256) {   // combine0 zero-state: c = i*g (copies 0..3)
            float pi = sm[BS0O + jc], pg = sm[BS0O + 128 + jc], po = sm[BS0O + 192 + jc];
#pragma unroll
            for (int cp = 0; cp < 4; ++cp) {
                const float* pp = sm + P0O + cp * 1024 + rc * 256;
                pi += pp[jc]; pg += pp[128 + jc]; po += pp[192 + jc];
            }
            const float ig = sigm(pi), gg = tanh_(pg), og = sigm(po);
            sm[H0O + tid] = og * tanh_(ig * gg);
        }
        __syncthreads();

        // ---- cell1 matvec: m==0 grps from H0 ----
        if (m == 0) {
            float a0=0.f,a1=0.f,a2=0.f,a3=0.f,a4=0.f,a5=0.f,a6=0.f,a7=0.f;
#pragma unroll
            for (int k4 = 0; k4 < 4; ++k4) {
                const float4 v0 = *reinterpret_cast<const float4*>(sm + H0O + 0 * 64 + ko + k4 * 4);
                const float4 v1 = *reinterpret_cast<const float4*>(sm + H0O + 1 * 64 + ko + k4 * 4);
                fma4v(a0, v0, w1a[k4]); fma4v(a1, v0, w1b[k4]);
                fma4v(a2, v1, w1a[k4]); fma4v(a3, v1, w1b[k4]);
                const float4 v2 = *reinterpret_cast<const float4*>(sm + H0O + 2 * 64 + ko + k4 * 4);
                const float4 v3 = *reinterpret_cast<const float4*>(sm + H0O + 3 * 64 + ko + k4 * 4);
                fma4v(a4, v2, w1a[k4]); fma4v(a5, v2, w1b[k4]);
                fma4v(a6, v3, w1a[k4]); fma4v(a7, v3, w1b[k4]);
            }
            sm[P1O + pb + 0 * 256 + g0] = a0; sm[P1O + pb + 0 * 256 + g1] = a1;
            sm[P1O + pb + 1 * 256 + g0] = a2; sm[P1O + pb + 1 * 256 + g1] = a3;
            sm[P1O + pb + 2 * 256 + g0] = a4; sm[P1O + pb + 2 * 256 + g1] = a5;
            sm[P1O + pb + 3 * 256 + g0] = a6; sm[P1O + pb + 3 * 256 + g1] = a7;
        }
        __syncthreads();
        if (tid >= 768) {  // combine1 zero-state (copies 0..3)
            float pi = sm[BS1O + jc], pg = sm[BS1O + 128 + jc], po = sm[BS1O + 192 + jc];
#pragma unroll
            for (int cp = 0; cp < 4; ++cp) {
                const float* pp = sm + P1O + cp * 1024 + rc * 256;
                pi += pp[jc]; pg += pp[128 + jc]; po += pp[192 + jc];
            }
            const float ig = sigm(pi), gg = tanh_(pg), og = sigm(po);
            sm[H1O + rc * 64 + jc] = og * tanh_(ig * gg);
        }
        __syncthreads();

        // ---- FC (tid<256): uniform h1 b128 + stride-1 b32 W_fc ----
        if (tid < 256) {
            float acc = bfc_j;
            const float4* hp = reinterpret_cast<const float4*>(sm + H1O + rc * 64);
#pragma unroll
            for (int k4 = 0; k4 < 16; ++k4) {
                const float4 hv = hp[k4];
                const float* wp = sm + WFCO + k4 * 256;
                acc = fmaf(hv.x, wp[jc],       acc);
                acc = fmaf(hv.y, wp[64 + jc],  acc);
                acc = fmaf(hv.z, wp[128 + jc], acc);
                acc = fmaf(hv.w, wp[192 + jc], acc);
            }
            out[(size_t)(row0 + rc) * PRED * DIM + p * DIM + jc] = acc;
            sm[DBO + tid] = acc;
        }
        __syncthreads();
    }
}

extern "C" void kernel_launch(void* const* d_in, const int* in_sizes, int n_in,
                              void* d_out, int out_size, void* d_ws, size_t ws_size,
                              hipStream_t stream) {
    const float* x    = (const float*)d_in[0];
    const float* Wih0 = (const float*)d_in[1];
    const float* Whh0 = (const float*)d_in[2];
    const float* bih0 = (const float*)d_in[3];
    const float* bhh0 = (const float*)d_in[4];
    const float* Wih1 = (const float*)d_in[5];
    const float* Whh1 = (const float*)d_in[6];
    const float* bih1 = (const float*)d_in[7];
    const float* bhh1 = (const float*)d_in[8];
    const float* Wfc  = (const float*)d_in[9];
    const float* bfc  = (const float*)d_in[10];
    float* out = (float*)d_out;

    // 87 KB dynamic LDS (>64 KB opt-in; idempotent, graph-capture safe)
    (void)hipFuncSetAttribute(reinterpret_cast<const void*>(rnn_fused),
                              hipFuncAttributeMaxDynamicSharedMemorySize, SMEM_BYTES);

    hipLaunchKernelGGL(rnn_fused, dim3(NB / ROWS), dim3(THREADS), SMEM_BYTES, stream,
                       x, Wih0, Whh0, bih0, bhh0, Wih1, Whh1, bih1, bhh1, Wfc, bfc, out);
}

// Round 7
// 2452.876 us; speedup vs baseline: 2.7766x; 1.2980x over previous
//
#include <hip/hip_runtime.h>

#define NB    1024
#define TSEQ  336
#define DIM   64
#define GATES 256
#define PRED  96
#define THREADS 1024
#define ROWS  4          // grid = 256 blocks, 1 block/CU, 16 waves (4/SIMD)

// LDS (float offsets), 87 KB. No weights in LDS (per-lane ds_read_b128 is
// ~8-way conflicted on gfx950 — R3). Weights live in VGPRs, pinned with empty
// asm to defeat the rematerializer (R5/R6: compiler re-loads weights from
// global every step when VGPR cap is 128 — FETCH blew up to GBs).
#define P0O   0        // layer-0 partials [8 copies][4 rows][256] = 8192
#define P1O   8192     // layer-1 partials [8][4][256] = 8192
#define WFCO  16384    // W_fc [16][4][64] : (k4,c,j) = W[j][4k4+c]
#define H0O   20480    // [4][64]
#define H1O   20736    // [4][64]
#define DBO   20992    // [4][64] decoder feedback
#define BS0O  21248    // 256
#define BS1O  21504    // 256
#define BFCO  21760    // 64
#define SMF   21824
#define SMEM_BYTES (SMF * 4)   // 87296 B -> dynamic-LDS opt-in

__device__ __forceinline__ float sigm(float v)  { return 1.0f / (1.0f + __expf(-v)); }
__device__ __forceinline__ float tanh_(float v) { return 1.0f - 2.0f / (__expf(2.0f * v) + 1.0f); }

__device__ __forceinline__ void fma4s(float& acc, const float4 xv, const float* w) {
    acc = fmaf(xv.x, w[0], acc); acc = fmaf(xv.y, w[1], acc);
    acc = fmaf(xv.z, w[2], acc); acc = fmaf(xv.w, w[3], acc);
}

extern "C" __global__ void __launch_bounds__(THREADS, 4)   // 4 waves/EU, VGPR cap 128
rnn_fused(const float* __restrict__ x,
          const float* __restrict__ Wih0, const float* __restrict__ Whh0,
          const float* __restrict__ bih0, const float* __restrict__ bhh0,
          const float* __restrict__ Wih1, const float* __restrict__ Whh1,
          const float* __restrict__ bih1, const float* __restrict__ bhh1,
          const float* __restrict__ Wfc,  const float* __restrict__ bfc,
          float* __restrict__ out)
{
    extern __shared__ float sm[];
    const int tid = threadIdx.x;
    const int bid = blockIdx.x;
    const int grp = tid >> 7;          // 0..7: partial-copy index
    const int m   = grp >> 2;          // 0: ih matrices, 1: hh matrices
    const int kq  = grp & 3;           // k-quarter
    const int ko  = kq * 16;           // k offset (floats)
    const int gp  = tid & 127;
    const int g0  = gp, g1 = gp + 128; // owned gate rows
    const int pb  = grp * 1024;        // partial base [copy][row][gate]

    const int rc = (tid & 255) >> 6;   // combine row
    const int jc = tid & 63;           // combine hidden index

    // ---- prologue staging ----
    if (tid < GATES) {
        sm[BS0O + tid] = bih0[tid] + bhh0[tid];
        sm[BS1O + tid] = bih1[tid] + bhh1[tid];
    }
    if (tid < DIM) sm[BFCO + tid] = bfc[tid];
    if (tid < 256) { sm[H0O + tid] = 0.0f; sm[H1O + tid] = 0.0f; }
    for (int idx = tid; idx < DIM * DIM; idx += THREADS) {   // W_fc: (k4,c,j)
        const int j = idx >> 6, k = idx & 63;
        sm[WFCO + (k >> 2) * 256 + (k & 3) * 64 + j] = Wfc[idx];
    }

    // ---- weights -> scalar registers, then PIN so the compiler cannot remat ----
    const float* Ws0 = m ? Whh0 : Wih0;
    const float* Ws1 = m ? Whh1 : Wih1;
    float w0a[16], w0b[16], w1a[16], w1b[16];
#pragma unroll
    for (int k4 = 0; k4 < 4; ++k4) {
        float4 t;
        t = *reinterpret_cast<const float4*>(Ws0 + g0 * DIM + ko + k4 * 4);
        w0a[k4*4+0]=t.x; w0a[k4*4+1]=t.y; w0a[k4*4+2]=t.z; w0a[k4*4+3]=t.w;
        t = *reinterpret_cast<const float4*>(Ws0 + g1 * DIM + ko + k4 * 4);
        w0b[k4*4+0]=t.x; w0b[k4*4+1]=t.y; w0b[k4*4+2]=t.z; w0b[k4*4+3]=t.w;
        t = *reinterpret_cast<const float4*>(Ws1 + g0 * DIM + ko + k4 * 4);
        w1a[k4*4+0]=t.x; w1a[k4*4+1]=t.y; w1a[k4*4+2]=t.z; w1a[k4*4+3]=t.w;
        t = *reinterpret_cast<const float4*>(Ws1 + g1 * DIM + ko + k4 * 4);
        w1b[k4*4+0]=t.x; w1b[k4*4+1]=t.y; w1b[k4*4+2]=t.z; w1b[k4*4+3]=t.w;
    }
#pragma unroll
    for (int i = 0; i < 16; ++i) {
        asm volatile("" : "+v"(w0a[i]), "+v"(w0b[i]), "+v"(w1a[i]), "+v"(w1b[i]));
    }
    __syncthreads();

    const int row0 = bid * ROWS;
    const float* xb = x + (size_t)row0 * TSEQ * DIM + ko;
    const size_t XRS = (size_t)TSEQ * DIM;

    float c_state = 0.0f;   // c0 for tid<256; c1 for tid>=768

    // ============ encoder: 336 steps, 3 barriers (combine1_{s-1} overlaps seg1) ============
    for (int s = 0; s < TSEQ; ++s) {
        // ---- seg1: combine1(s-1) on tid>=768, + layer-0 matvec all ----
        if (s != 0 && tid >= 768) {
            float pi = sm[BS1O + jc],       pf = sm[BS1O + 64 + jc];
            float pg = sm[BS1O + 128 + jc], po = sm[BS1O + 192 + jc];
#pragma unroll
            for (int cp = 0; cp < 8; ++cp) {
                const float* p = sm + P1O + cp * 1024 + rc * 256;
                pi += p[jc]; pf += p[64 + jc]; pg += p[128 + jc]; po += p[192 + jc];
            }
            const float ig = sigm(pi), fg = sigm(pf), gg = tanh_(pg), og = sigm(po);
            c_state = fmaf(fg, c_state, ig * gg);
            sm[H1O + rc * 64 + jc] = og * tanh_(c_state);
        }
        {
            float a0=0.f,a1=0.f,a2=0.f,a3=0.f,a4=0.f,a5=0.f,a6=0.f,a7=0.f;
            if (m == 0) {        // x-part: global loads (VMEM pipe)
                const float* xs = xb + (size_t)s * DIM;
#pragma unroll
                for (int k4 = 0; k4 < 4; ++k4) {
                    const float4 v0 = *reinterpret_cast<const float4*>(xs + 0 * XRS + k4 * 4);
                    const float4 v1 = *reinterpret_cast<const float4*>(xs + 1 * XRS + k4 * 4);
                    fma4s(a0, v0, w0a + k4*4); fma4s(a1, v0, w0b + k4*4);
                    fma4s(a2, v1, w0a + k4*4); fma4s(a3, v1, w0b + k4*4);
                    const float4 v2 = *reinterpret_cast<const float4*>(xs + 2 * XRS + k4 * 4);
                    const float4 v3 = *reinterpret_cast<const float4*>(xs + 3 * XRS + k4 * 4);
                    fma4s(a4, v2, w0a + k4*4); fma4s(a5, v2, w0b + k4*4);
                    fma4s(a6, v3, w0a + k4*4); fma4s(a7, v3, w0b + k4*4);
                }
            } else {             // h-part: wave-uniform LDS b128 broadcasts (free)
#pragma unroll
                for (int k4 = 0; k4 < 4; ++k4) {
                    const float4 v0 = *reinterpret_cast<const float4*>(sm + H0O + 0 * 64 + ko + k4 * 4);
                    const float4 v1 = *reinterpret_cast<const float4*>(sm + H0O + 1 * 64 + ko + k4 * 4);
                    fma4s(a0, v0, w0a + k4*4); fma4s(a1, v0, w0b + k4*4);
                    fma4s(a2, v1, w0a + k4*4); fma4s(a3, v1, w0b + k4*4);
                    const float4 v2 = *reinterpret_cast<const float4*>(sm + H0O + 2 * 64 + ko + k4 * 4);
                    const float4 v3 = *reinterpret_cast<const float4*>(sm + H0O + 3 * 64 + ko + k4 * 4);
                    fma4s(a4, v2, w0a + k4*4); fma4s(a5, v2, w0b + k4*4);
                    fma4s(a6, v3, w0a + k4*4); fma4s(a7, v3, w0b + k4*4);
                }
            }
            sm[P0O + pb + 0 * 256 + g0] = a0; sm[P0O + pb + 0 * 256 + g1] = a1;
            sm[P0O + pb + 1 * 256 + g0] = a2; sm[P0O + pb + 1 * 256 + g1] = a3;
            sm[P0O + pb + 2 * 256 + g0] = a4; sm[P0O + pb + 2 * 256 + g1] = a5;
            sm[P0O + pb + 3 * 256 + g0] = a6; sm[P0O + pb + 3 * 256 + g1] = a7;
        }
        __syncthreads();

        // ---- seg2: combine0 on tid<256 ----
        if (tid < 256) {
            float pi = sm[BS0O + jc],       pf = sm[BS0O + 64 + jc];
            float pg = sm[BS0O + 128 + jc], po = sm[BS0O + 192 + jc];
#pragma unroll
            for (int cp = 0; cp < 8; ++cp) {
                const float* p = sm + P0O + cp * 1024 + rc * 256;
                pi += p[jc]; pf += p[64 + jc]; pg += p[128 + jc]; po += p[192 + jc];
            }
            const float ig = sigm(pi), fg = sigm(pf), gg = tanh_(pg), og = sigm(po);
            c_state = fmaf(fg, c_state, ig * gg);
            sm[H0O + tid] = og * tanh_(c_state);
        }
        __syncthreads();

        // ---- seg3: layer-1 matvec (m selects h0_s / h1_{s-1}) ----
        {
            const int ib = m ? H1O : H0O;
            float a0=0.f,a1=0.f,a2=0.f,a3=0.f,a4=0.f,a5=0.f,a6=0.f,a7=0.f;
#pragma unroll
            for (int k4 = 0; k4 < 4; ++k4) {
                const float4 v0 = *reinterpret_cast<const float4*>(sm + ib + 0 * 64 + ko + k4 * 4);
                const float4 v1 = *reinterpret_cast<const float4*>(sm + ib + 1 * 64 + ko + k4 * 4);
                fma4s(a0, v0, w1a + k4*4); fma4s(a1, v0, w1b + k4*4);
                fma4s(a2, v1, w1a + k4*4); fma4s(a3, v1, w1b + k4*4);
                const float4 v2 = *reinterpret_cast<const float4*>(sm + ib + 2 * 64 + ko + k4 * 4);
                const float4 v3 = *reinterpret_cast<const float4*>(sm + ib + 3 * 64 + ko + k4 * 4);
                fma4s(a4, v2, w1a + k4*4); fma4s(a5, v2, w1b + k4*4);
                fma4s(a6, v3, w1a + k4*4); fma4s(a7, v3, w1b + k4*4);
            }
            sm[P1O + pb + 0 * 256 + g0] = a0; sm[P1O + pb + 0 * 256 + g1] = a1;
            sm[P1O + pb + 1 * 256 + g0] = a2; sm[P1O + pb + 1 * 256 + g1] = a3;
            sm[P1O + pb + 2 * 256 + g0] = a4; sm[P1O + pb + 2 * 256 + g1] = a5;
            sm[P1O + pb + 3 * 256 + g0] = a6; sm[P1O + pb + 3 * 256 + g1] = a7;
        }
        __syncthreads();
    }

    // ---- final combine1 (s=335) -> decoder carry ----
    if (tid >= 768) {
        float pi = sm[BS1O + jc],       pf = sm[BS1O + 64 + jc];
        float pg = sm[BS1O + 128 + jc], po = sm[BS1O + 192 + jc];
#pragma unroll
        for (int cp = 0; cp < 8; ++cp) {
            const float* p = sm + P1O + cp * 1024 + rc * 256;
            pi += p[jc]; pf += p[64 + jc]; pg += p[128 + jc]; po += p[192 + jc];
        }
        const float ig = sigm(pi), fg = sigm(pf), gg = tanh_(pg), og = sigm(po);
        c_state = fmaf(fg, c_state, ig * gg);
        sm[DBO + rc * 64 + jc] = og * tanh_(c_state);
    }
    __syncthreads();

    const float bfc_j = sm[BFCO + jc];

    // ============ decoder: 96 autoregressive steps (zero-state cells) ============
    for (int p = 0; p < PRED; ++p) {
        // ---- cell0 matvec: m==0 grps from DBO ----
        if (m == 0) {
            float a0=0.f,a1=0.f,a2=0.f,a3=0.f,a4=0.f,a5=0.f,a6=0.f,a7=0.f;
#pragma unroll
            for (int k4 = 0; k4 < 4; ++k4) {
                const float4 v0 = *reinterpret_cast<const float4*>(sm + DBO + 0 * 64 + ko + k4 * 4);
                const float4 v1 = *reinterpret_cast<const float4*>(sm + DBO + 1 * 64 + ko + k4 * 4);
                fma4s(a0, v0, w0a + k4*4); fma4s(a1, v0, w0b + k4*4);
                fma4s(a2, v1, w0a + k4*4); fma4s(a3, v1, w0b + k4*4);
                const float4 v2 = *reinterpret_cast<const float4*>(sm + DBO + 2 * 64 + ko + k4 * 4);
                const float4 v3 = *reinterpret_cast<const float4*>(sm + DBO + 3 * 64 + ko + k4 * 4);
                fma4s(a4, v2, w0a + k4*4); fma4s(a5, v2, w0b + k4*4);
                fma4s(a6, v3, w0a + k4*4); fma4s(a7, v3, w0b + k4*4);
            }
            sm[P0O + pb + 0 * 256 + g0] = a0; sm[P0O + pb + 0 * 256 + g1] = a1;
            sm[P0O + pb + 1 * 256 + g0] = a2; sm[P0O + pb + 1 * 256 + g1] = a3;
            sm[P0O + pb + 2 * 256 + g0] = a4; sm[P0O + pb + 2 * 256 + g1] = a5;
            sm[P0O + pb + 3 * 256 + g0] = a6; sm[P0O + pb + 3 * 256 + g1] = a7;
        }
        __syncthreads();
        if (tid < 256) {   // combine0 zero-state: c = i*g (copies 0..3)
            float pi = sm[BS0O + jc], pg = sm[BS0O + 128 + jc], po = sm[BS0O + 192 + jc];
#pragma unroll
            for (int cp = 0; cp < 4; ++cp) {
                const float* pp = sm + P0O + cp * 1024 + rc * 256;
                pi += pp[jc]; pg += pp[128 + jc]; po += pp[192 + jc];
            }
            const float ig = sigm(pi), gg = tanh_(pg), og = sigm(po);
            sm[H0O + tid] = og * tanh_(ig * gg);
        }
        __syncthreads();

        // ---- cell1 matvec: m==0 grps from H0 ----
        if (m == 0) {
            float a0=0.f,a1=0.f,a2=0.f,a3=0.f,a4=0.f,a5=0.f,a6=0.f,a7=0.f;
#pragma unroll
            for (int k4 = 0; k4 < 4; ++k4) {
                const float4 v0 = *reinterpret_cast<const float4*>(sm + H0O + 0 * 64 + ko + k4 * 4);
                const float4 v1 = *reinterpret_cast<const float4*>(sm + H0O + 1 * 64 + ko + k4 * 4);
                fma4s(a0, v0, w1a + k4*4); fma4s(a1, v0, w1b + k4*4);
                fma4s(a2, v1, w1a + k4*4); fma4s(a3, v1, w1b + k4*4);
                const float4 v2 = *reinterpret_cast<const float4*>(sm + H0O + 2 * 64 + ko + k4 * 4);
                const float4 v3 = *reinterpret_cast<const float4*>(sm + H0O + 3 * 64 + ko + k4 * 4);
                fma4s(a4, v2, w1a + k4*4); fma4s(a5, v2, w1b + k4*4);
                fma4s(a6, v3, w1a + k4*4); fma4s(a7, v3, w1b + k4*4);
            }
            sm[P1O + pb + 0 * 256 + g0] = a0; sm[P1O + pb + 0 * 256 + g1] = a1;
            sm[P1O + pb + 1 * 256 + g0] = a2; sm[P1O + pb + 1 * 256 + g1] = a3;
            sm[P1O + pb + 2 * 256 + g0] = a4; sm[P1O + pb + 2 * 256 + g1] = a5;
            sm[P1O + pb + 3 * 256 + g0] = a6; sm[P1O + pb + 3 * 256 + g1] = a7;
        }
        __syncthreads();
        if (tid >= 768) {  // combine1 zero-state (copies 0..3)
            float pi = sm[BS1O + jc], pg = sm[BS1O + 128 + jc], po = sm[BS1O + 192 + jc];
#pragma unroll
            for (int cp = 0; cp < 4; ++cp) {
                const float* pp = sm + P1O + cp * 1024 + rc * 256;
                pi += pp[jc]; pg += pp[128 + jc]; po += pp[192 + jc];
            }
            const float ig = sigm(pi), gg = tanh_(pg), og = sigm(po);
            sm[H1O + rc * 64 + jc] = og * tanh_(ig * gg);
        }
        __syncthreads();

        // ---- FC (tid<256): uniform h1 b128 + stride-1 b32 W_fc ----
        if (tid < 256) {
            float acc = bfc_j;
            const float4* hp = reinterpret_cast<const float4*>(sm + H1O + rc * 64);
#pragma unroll
            for (int k4 = 0; k4 < 16; ++k4) {
                const float4 hv = hp[k4];
                const float* wp = sm + WFCO + k4 * 256;
                acc = fmaf(hv.x, wp[jc],       acc);
                acc = fmaf(hv.y, wp[64 + jc],  acc);
                acc = fmaf(hv.z, wp[128 + jc], acc);
                acc = fmaf(hv.w, wp[192 + jc], acc);
            }
            out[(size_t)(row0 + rc) * PRED * DIM + p * DIM + jc] = acc;
            sm[DBO + tid] = acc;
        }
        __syncthreads();
    }
}

extern "C" void kernel_launch(void* const* d_in, const int* in_sizes, int n_in,
                              void* d_out, int out_size, void* d_ws, size_t ws_size,
                              hipStream_t stream) {
    const float* x    = (const float*)d_in[0];
    const float* Wih0 = (const float*)d_in[1];
    const float* Whh0 = (const float*)d_in[2];
    const float* bih0 = (const float*)d_in[3];
    const float* bhh0 = (const float*)d_in[4];
    const float* Wih1 = (const float*)d_in[5];
    const float* Whh1 = (const float*)d_in[6];
    const float* bih1 = (const float*)d_in[7];
    const float* bhh1 = (const float*)d_in[8];
    const float* Wfc  = (const float*)d_in[9];
    const float* bfc  = (const float*)d_in[10];
    float* out = (float*)d_out;

    (void)hipFuncSetAttribute(reinterpret_cast<const void*>(rnn_fused),
                              hipFuncAttributeMaxDynamicSharedMemorySize, SMEM_BYTES);

    hipLaunchKernelGGL(rnn_fused, dim3(NB / ROWS), dim3(THREADS), SMEM_BYTES, stream,
                       x, Wih0, Whh0, bih0, bhh0, Wih1, Whh1, bih1, bhh1, Wfc, bfc, out);
}

// Round 8
// 2441.320 us; speedup vs baseline: 2.7897x; 1.0047x over previous
//
#include <hip/hip_runtime.h>

#define NB    1024
#define TSEQ  336
#define DIM   64
#define GATES 256
#define PRED  96
#define THREADS 1024
#define ROWS  4          // grid = 256 blocks, 1 block/CU, 16 waves (4/SIMD)

// LDS (float offsets), 87 KB. No weights in LDS (per-lane ds_read_b128 is
// ~8-way conflicted on gfx950 — R3). Weights pinned in VGPRs. KEY FIX (R8):
// amdgpu_waves_per_eu(4,4) — launch_bounds' 2nd arg is only a MINIMUM; the
// backend still targets 8 waves/EU (64-VGPR budget) and remats (R6) or
// spills (R7) the weights. Pinning the occupancy ceiling at 4 gives a firm
// 128-VGPR budget for our ~104-VGPR need.
#define P0O   0        // layer-0 partials [8 copies][4 rows][256] = 8192
#define P1O   8192     // layer-1 partials [8][4][256] = 8192
#define WFCO  16384    // W_fc [16][4][64] : (k4,c,j) = W[j][4k4+c]
#define H0O   20480    // [4][64]
#define H1O   20736    // [4][64]
#define DBO   20992    // [4][64] decoder feedback
#define BS0O  21248    // 256
#define BS1O  21504    // 256
#define BFCO  21760    // 64
#define SMF   21824
#define SMEM_BYTES (SMF * 4)   // 87296 B -> dynamic-LDS opt-in

__device__ __forceinline__ float sigm(float v)  { return 1.0f / (1.0f + __expf(-v)); }
__device__ __forceinline__ float tanh_(float v) { return 1.0f - 2.0f / (__expf(2.0f * v) + 1.0f); }

__device__ __forceinline__ void fma4s(float& acc, const float4 xv, const float* w) {
    acc = fmaf(xv.x, w[0], acc); acc = fmaf(xv.y, w[1], acc);
    acc = fmaf(xv.z, w[2], acc); acc = fmaf(xv.w, w[3], acc);
}

extern "C" __global__ void
__launch_bounds__(THREADS)
__attribute__((amdgpu_waves_per_eu(4, 4)))   // firm 128-VGPR budget, no 8-wave target
rnn_fused(const float* __restrict__ x,
          const float* __restrict__ Wih0, const float* __restrict__ Whh0,
          const float* __restrict__ bih0, const float* __restrict__ bhh0,
          const float* __restrict__ Wih1, const float* __restrict__ Whh1,
          const float* __restrict__ bih1, const float* __restrict__ bhh1,
          const float* __restrict__ Wfc,  const float* __restrict__ bfc,
          float* __restrict__ out)
{
    extern __shared__ float sm[];
    const int tid = threadIdx.x;
    const int bid = blockIdx.x;
    const int grp = tid >> 7;          // 0..7: partial-copy index
    const int m   = grp >> 2;          // 0: ih matrices, 1: hh matrices
    const int kq  = grp & 3;           // k-quarter
    const int ko  = kq * 16;           // k offset (floats)
    const int gp  = tid & 127;
    const int g0  = gp, g1 = gp + 128; // owned gate rows
    const int pb  = grp * 1024;        // partial base [copy][row][gate]

    const int rc = (tid & 255) >> 6;   // combine row
    const int jc = tid & 63;           // combine hidden index

    // ---- prologue staging ----
    if (tid < GATES) {
        sm[BS0O + tid] = bih0[tid] + bhh0[tid];
        sm[BS1O + tid] = bih1[tid] + bhh1[tid];
    }
    if (tid < DIM) sm[BFCO + tid] = bfc[tid];
    if (tid < 256) { sm[H0O + tid] = 0.0f; sm[H1O + tid] = 0.0f; }
    for (int idx = tid; idx < DIM * DIM; idx += THREADS) {   // W_fc: (k4,c,j)
        const int j = idx >> 6, k = idx & 63;
        sm[WFCO + (k >> 2) * 256 + (k & 3) * 64 + j] = Wfc[idx];
    }

    // ---- weights -> scalar registers, then PIN (anti-remat / anti-spill) ----
    const float* Ws0 = m ? Whh0 : Wih0;
    const float* Ws1 = m ? Whh1 : Wih1;
    float w0a[16], w0b[16], w1a[16], w1b[16];
#pragma unroll
    for (int k4 = 0; k4 < 4; ++k4) {
        float4 t;
        t = *reinterpret_cast<const float4*>(Ws0 + g0 * DIM + ko + k4 * 4);
        w0a[k4*4+0]=t.x; w0a[k4*4+1]=t.y; w0a[k4*4+2]=t.z; w0a[k4*4+3]=t.w;
        t = *reinterpret_cast<const float4*>(Ws0 + g1 * DIM + ko + k4 * 4);
        w0b[k4*4+0]=t.x; w0b[k4*4+1]=t.y; w0b[k4*4+2]=t.z; w0b[k4*4+3]=t.w;
        t = *reinterpret_cast<const float4*>(Ws1 + g0 * DIM + ko + k4 * 4);
        w1a[k4*4+0]=t.x; w1a[k4*4+1]=t.y; w1a[k4*4+2]=t.z; w1a[k4*4+3]=t.w;
        t = *reinterpret_cast<const float4*>(Ws1 + g1 * DIM + ko + k4 * 4);
        w1b[k4*4+0]=t.x; w1b[k4*4+1]=t.y; w1b[k4*4+2]=t.z; w1b[k4*4+3]=t.w;
    }
#pragma unroll
    for (int i = 0; i < 16; ++i) {
        asm volatile("" : "+v"(w0a[i]), "+v"(w0b[i]), "+v"(w1a[i]), "+v"(w1b[i]));
    }
    __syncthreads();

    const int row0 = bid * ROWS;
    const float* xb = x + (size_t)row0 * TSEQ * DIM + ko;
    const size_t XRS = (size_t)TSEQ * DIM;

    float c_state = 0.0f;   // c0 for tid<256; c1 for tid>=768

    // ============ encoder: 336 steps, 3 barriers (combine1_{s-1} overlaps seg1) ============
    for (int s = 0; s < TSEQ; ++s) {
        // ---- seg1: combine1(s-1) on tid>=768, + layer-0 matvec all ----
        if (s != 0 && tid >= 768) {
            float pi = sm[BS1O + jc],       pf = sm[BS1O + 64 + jc];
            float pg = sm[BS1O + 128 + jc], po = sm[BS1O + 192 + jc];
#pragma unroll
            for (int cp = 0; cp < 8; ++cp) {
                const float* p = sm + P1O + cp * 1024 + rc * 256;
                pi += p[jc]; pf += p[64 + jc]; pg += p[128 + jc]; po += p[192 + jc];
            }
            const float ig = sigm(pi), fg = sigm(pf), gg = tanh_(pg), og = sigm(po);
            c_state = fmaf(fg, c_state, ig * gg);
            sm[H1O + rc * 64 + jc] = og * tanh_(c_state);
        }
        {
            float a0=0.f,a1=0.f,a2=0.f,a3=0.f,a4=0.f,a5=0.f,a6=0.f,a7=0.f;
            if (m == 0) {        // x-part: global loads (VMEM pipe)
                const float* xs = xb + (size_t)s * DIM;
#pragma unroll
                for (int k4 = 0; k4 < 4; ++k4) {
                    const float4 v0 = *reinterpret_cast<const float4*>(xs + 0 * XRS + k4 * 4);
                    const float4 v1 = *reinterpret_cast<const float4*>(xs + 1 * XRS + k4 * 4);
                    fma4s(a0, v0, w0a + k4*4); fma4s(a1, v0, w0b + k4*4);
                    fma4s(a2, v1, w0a + k4*4); fma4s(a3, v1, w0b + k4*4);
                    const float4 v2 = *reinterpret_cast<const float4*>(xs + 2 * XRS + k4 * 4);
                    const float4 v3 = *reinterpret_cast<const float4*>(xs + 3 * XRS + k4 * 4);
                    fma4s(a4, v2, w0a + k4*4); fma4s(a5, v2, w0b + k4*4);
                    fma4s(a6, v3, w0a + k4*4); fma4s(a7, v3, w0b + k4*4);
                }
            } else {             // h-part: wave-uniform LDS b128 broadcasts (free)
#pragma unroll
                for (int k4 = 0; k4 < 4; ++k4) {
                    const float4 v0 = *reinterpret_cast<const float4*>(sm + H0O + 0 * 64 + ko + k4 * 4);
                    const float4 v1 = *reinterpret_cast<const float4*>(sm + H0O + 1 * 64 + ko + k4 * 4);
                    fma4s(a0, v0, w0a + k4*4); fma4s(a1, v0, w0b + k4*4);
                    fma4s(a2, v1, w0a + k4*4); fma4s(a3, v1, w0b + k4*4);
                    const float4 v2 = *reinterpret_cast<const float4*>(sm + H0O + 2 * 64 + ko + k4 * 4);
                    const float4 v3 = *reinterpret_cast<const float4*>(sm + H0O + 3 * 64 + ko + k4 * 4);
                    fma4s(a4, v2, w0a + k4*4); fma4s(a5, v2, w0b + k4*4);
                    fma4s(a6, v3, w0a + k4*4); fma4s(a7, v3, w0b + k4*4);
                }
            }
            sm[P0O + pb + 0 * 256 + g0] = a0; sm[P0O + pb + 0 * 256 + g1] = a1;
            sm[P0O + pb + 1 * 256 + g0] = a2; sm[P0O + pb + 1 * 256 + g1] = a3;
            sm[P0O + pb + 2 * 256 + g0] = a4; sm[P0O + pb + 2 * 256 + g1] = a5;
            sm[P0O + pb + 3 * 256 + g0] = a6; sm[P0O + pb + 3 * 256 + g1] = a7;
        }
        __syncthreads();

        // ---- seg2: combine0 on tid<256 ----
        if (tid < 256) {
            float pi = sm[BS0O + jc],       pf = sm[BS0O + 64 + jc];
            float pg = sm[BS0O + 128 + jc], po = sm[BS0O + 192 + jc];
#pragma unroll
            for (int cp = 0; cp < 8; ++cp) {
                const float* p = sm + P0O + cp * 1024 + rc * 256;
                pi += p[jc]; pf += p[64 + jc]; pg += p[128 + jc]; po += p[192 + jc];
            }
            const float ig = sigm(pi), fg = sigm(pf), gg = tanh_(pg), og = sigm(po);
            c_state = fmaf(fg, c_state, ig * gg);
            sm[H0O + tid] = og * tanh_(c_state);
        }
        __syncthreads();

        // ---- seg3: layer-1 matvec (m selects h0_s / h1_{s-1}) ----
        {
            const int ib = m ? H1O : H0O;
            float a0=0.f,a1=0.f,a2=0.f,a3=0.f,a4=0.f,a5=0.f,a6=0.f,a7=0.f;
#pragma unroll
            for (int k4 = 0; k4 < 4; ++k4) {
                const float4 v0 = *reinterpret_cast<const float4*>(sm + ib + 0 * 64 + ko + k4 * 4);
                const float4 v1 = *reinterpret_cast<const float4*>(sm + ib + 1 * 64 + ko + k4 * 4);
                fma4s(a0, v0, w1a + k4*4); fma4s(a1, v0, w1b + k4*4);
                fma4s(a2, v1, w1a + k4*4); fma4s(a3, v1, w1b + k4*4);
                const float4 v2 = *reinterpret_cast<const float4*>(sm + ib + 2 * 64 + ko + k4 * 4);
                const float4 v3 = *reinterpret_cast<const float4*>(sm + ib + 3 * 64 + ko + k4 * 4);
                fma4s(a4, v2, w1a + k4*4); fma4s(a5, v2, w1b + k4*4);
                fma4s(a6, v3, w1a + k4*4); fma4s(a7, v3, w1b + k4*4);
            }
            sm[P1O + pb + 0 * 256 + g0] = a0; sm[P1O + pb + 0 * 256 + g1] = a1;
            sm[P1O + pb + 1 * 256 + g0] = a2; sm[P1O + pb + 1 * 256 + g1] = a3;
            sm[P1O + pb + 2 * 256 + g0] = a4; sm[P1O + pb + 2 * 256 + g1] = a5;
            sm[P1O + pb + 3 * 256 + g0] = a6; sm[P1O + pb + 3 * 256 + g1] = a7;
        }
        __syncthreads();
    }

    // ---- final combine1 (s=335) -> decoder carry ----
    if (tid >= 768) {
        float pi = sm[BS1O + jc],       pf = sm[BS1O + 64 + jc];
        float pg = sm[BS1O + 128 + jc], po = sm[BS1O + 192 + jc];
#pragma unroll
        for (int cp = 0; cp < 8; ++cp) {
            const float* p = sm + P1O + cp * 1024 + rc * 256;
            pi += p[jc]; pf += p[64 + jc]; pg += p[128 + jc]; po += p[192 + jc];
        }
        const float ig = sigm(pi), fg = sigm(pf), gg = tanh_(pg), og = sigm(po);
        c_state = fmaf(fg, c_state, ig * gg);
        sm[DBO + rc * 64 + jc] = og * tanh_(c_state);
    }
    __syncthreads();

    const float bfc_j = sm[BFCO + jc];

    // ============ decoder: 96 autoregressive steps (zero-state cells) ============
    for (int p = 0; p < PRED; ++p) {
        // ---- cell0 matvec: m==0 grps from DBO ----
        if (m == 0) {
            float a0=0.f,a1=0.f,a2=0.f,a3=0.f,a4=0.f,a5=0.f,a6=0.f,a7=0.f;
#pragma unroll
            for (int k4 = 0; k4 < 4; ++k4) {
                const float4 v0 = *reinterpret_cast<const float4*>(sm + DBO + 0 * 64 + ko + k4 * 4);
                const float4 v1 = *reinterpret_cast<const float4*>(sm + DBO + 1 * 64 + ko + k4 * 4);
                fma4s(a0, v0, w0a + k4*4); fma4s(a1, v0, w0b + k4*4);
                fma4s(a2, v1, w0a + k4*4); fma4s(a3, v1, w0b + k4*4);
                const float4 v2 = *reinterpret_cast<const float4*>(sm + DBO + 2 * 64 + ko + k4 * 4);
                const float4 v3 = *reinterpret_cast<const float4*>(sm + DBO + 3 * 64 + ko + k4 * 4);
                fma4s(a4, v2, w0a + k4*4); fma4s(a5, v2, w0b + k4*4);
                fma4s(a6, v3, w0a + k4*4); fma4s(a7, v3, w0b + k4*4);
            }
            sm[P0O + pb + 0 * 256 + g0] = a0; sm[P0O + pb + 0 * 256 + g1] = a1;
            sm[P0O + pb + 1 * 256 + g0] = a2; sm[P0O + pb + 1 * 256 + g1] = a3;
            sm[P0O + pb + 2 * 256 + g0] = a4; sm[P0O + pb + 2 * 256 + g1] = a5;
            sm[P0O + pb + 3 * 256 + g0] = a6; sm[P0O + pb + 3 * 256 + g1] = a7;
        }
        __syncthreads();
        if (tid < 256) {   // combine0 zero-state: c = i*g (copies 0..3)
            float pi = sm[BS0O + jc], pg = sm[BS0O + 128 + jc], po = sm[BS0O + 192 + jc];
#pragma unroll
            for (int cp = 0; cp < 4; ++cp) {
                const float* pp = sm + P0O + cp * 1024 + rc * 256;
                pi += pp[jc]; pg += pp[128 + jc]; po += pp[192 + jc];
            }
            const float ig = sigm(pi), gg = tanh_(pg), og = sigm(po);
            sm[H0O + tid] = og * tanh_(ig * gg);
        }
        __syncthreads();

        // ---- cell1 matvec: m==0 grps from H0 ----
        if (m == 0) {
            float a0=0.f,a1=0.f,a2=0.f,a3=0.f,a4=0.f,a5=0.f,a6=0.f,a7=0.f;
#pragma unroll
            for (int k4 = 0; k4 < 4; ++k4) {
                const float4 v0 = *reinterpret_cast<const float4*>(sm + H0O + 0 * 64 + ko + k4 * 4);
                const float4 v1 = *reinterpret_cast<const float4*>(sm + H0O + 1 * 64 + ko + k4 * 4);
                fma4s(a0, v0, w1a + k4*4); fma4s(a1, v0, w1b + k4*4);
                fma4s(a2, v1, w1a + k4*4); fma4s(a3, v1, w1b + k4*4);
                const float4 v2 = *reinterpret_cast<const float4*>(sm + H0O + 2 * 64 + ko + k4 * 4);
                const float4 v3 = *reinterpret_cast<const float4*>(sm + H0O + 3 * 64 + ko + k4 * 4);
                fma4s(a4, v2, w1a + k4*4); fma4s(a5, v2, w1b + k4*4);
                fma4s(a6, v3, w1a + k4*4); fma4s(a7, v3, w1b + k4*4);
            }
            sm[P1O + pb + 0 * 256 + g0] = a0; sm[P1O + pb + 0 * 256 + g1] = a1;
            sm[P1O + pb + 1 * 256 + g0] = a2; sm[P1O + pb + 1 * 256 + g1] = a3;
            sm[P1O + pb + 2 * 256 + g0] = a4; sm[P1O + pb + 2 * 256 + g1] = a5;
            sm[P1O + pb + 3 * 256 + g0] = a6; sm[P1O + pb + 3 * 256 + g1] = a7;
        }
        __syncthreads();
        if (tid >= 768) {  // combine1 zero-state (copies 0..3)
            float pi = sm[BS1O + jc], pg = sm[BS1O + 128 + jc], po = sm[BS1O + 192 + jc];
#pragma unroll
            for (int cp = 0; cp < 4; ++cp) {
                const float* pp = sm + P1O + cp * 1024 + rc * 256;
                pi += pp[jc]; pg += pp[128 + jc]; po += pp[192 + jc];
            }
            const float ig = sigm(pi), gg = tanh_(pg), og = sigm(po);
            sm[H1O + rc * 64 + jc] = og * tanh_(ig * gg);
        }
        __syncthreads();

        // ---- FC (tid<256): uniform h1 b128 + stride-1 b32 W_fc ----
        if (tid < 256) {
            float acc = bfc_j;
            const float4* hp = reinterpret_cast<const float4*>(sm + H1O + rc * 64);
#pragma unroll
            for (int k4 = 0; k4 < 16; ++k4) {
                const float4 hv = hp[k4];
                const float* wp = sm + WFCO + k4 * 256;
                acc = fmaf(hv.x, wp[jc],       acc);
                acc = fmaf(hv.y, wp[64 + jc],  acc);
                acc = fmaf(hv.z, wp[128 + jc], acc);
                acc = fmaf(hv.w, wp[192 + jc], acc);
            }
            out[(size_t)(row0 + rc) * PRED * DIM + p * DIM + jc] = acc;
            sm[DBO + tid] = acc;
        }
        __syncthreads();
    }
}

extern "C" void kernel_launch(void* const* d_in, const int* in_sizes, int n_in,
                              void* d_out, int out_size, void* d_ws, size_t ws_size,
                              hipStream_t stream) {
    const float* x    = (const float*)d_in[0];
    const float* Wih0 = (const float*)d_in[1];
    const float* Whh0 = (const float*)d_in[2];
    const float* bih0 = (const float*)d_in[3];
    const float* bhh0 = (const float*)d_in[4];
    const float* Wih1 = (const float*)d_in[5];
    const float* Whh1 = (const float*)d_in[6];
    const float* bih1 = (const float*)d_in[7];
    const float* bhh1 = (const float*)d_in[8];
    const float* Wfc  = (const float*)d_in[9];
    const float* bfc  = (const float*)d_in[10];
    float* out = (float*)d_out;

    (void)hipFuncSetAttribute(reinterpret_cast<const void*>(rnn_fused),
                              hipFuncAttributeMaxDynamicSharedMemorySize, SMEM_BYTES);

    hipLaunchKernelGGL(rnn_fused, dim3(NB / ROWS), dim3(THREADS), SMEM_BYTES, stream,
                       x, Wih0, Whh0, bih0, bhh0, Wih1, Whh1, bih1, bhh1, Wfc, bfc, out);
}

// Round 9
// 1854.635 us; speedup vs baseline: 3.6722x; 1.3163x over previous
//
#include <hip/hip_runtime.h>

#define NB    1024
#define TSEQ  336
#define DIM   64
#define GATES 256
#define PRED  96
#define THREADS 512
#define ROWS  2          // grid = NB/ROWS = 512 blocks

// LDS (float offsets), 36.6 KB — the R4 shape, the ONLY config where the
// compiler holds 128 weight floats in VGPRs with zero spill/remat
// (512 thr + launch_bounds(512,2) + float4 arrays; R5-R8 all failed).
#define P0O   0        // layer-0 partials [4 copies][2 rows][256] = 2048
#define P1O   2048     // layer-1 partials [4][2][256] = 2048
#define WFCO  4096     // W_fc [16][4][64] : (k4,c,j) = W[j][4k4+c]
#define H0O   8192     // [2][64]
#define H1O   8320     // [2][64]
#define DBO   8448     // [2][64]
#define BS0O  8576     // 256
#define BS1O  8832     // 256
#define BFCO  9088     // 64
#define SMF   9152
#define SMEM_BYTES (SMF * 4)

__device__ __forceinline__ float sigm(float v)  { return 1.0f / (1.0f + __expf(-v)); }
__device__ __forceinline__ float tanh_(float v) { return 1.0f - 2.0f / (__expf(2.0f * v) + 1.0f); }

__device__ __forceinline__ void fma4v(float& acc, const float4 xv, const float4 w) {
    acc = fmaf(xv.x, w.x, acc); acc = fmaf(xv.y, w.y, acc);
    acc = fmaf(xv.z, w.z, acc); acc = fmaf(xv.w, w.w, acc);
}

extern "C" __global__ void __launch_bounds__(THREADS, 2)   // R4's proven register regime
rnn_fused(const float* __restrict__ x,
          const float* __restrict__ Wih0, const float* __restrict__ Whh0,
          const float* __restrict__ bih0, const float* __restrict__ bhh0,
          const float* __restrict__ Wih1, const float* __restrict__ Whh1,
          const float* __restrict__ bih1, const float* __restrict__ bhh1,
          const float* __restrict__ Wfc,  const float* __restrict__ bfc,
          float* __restrict__ out)
{
    extern __shared__ float sm[];
    const int tid = threadIdx.x;
    const int bid = blockIdx.x;
    const int grp = tid >> 7;          // 0..3: partial-copy index
    const int m   = grp & 1;           // 0: ih matrices, 1: hh matrices
    const int kh  = grp >> 1;          // k-half
    const int gp  = tid & 127;
    const int g0  = gp, g1 = gp + 128;
    const int pb  = grp * 512;         // partial base [copy][row][gate]
    const int rc  = (tid & 127) >> 6;  // combine row
    const int jc  = tid & 63;          // combine hidden index

    // ---- prologue staging ----
    if (tid < GATES) {
        sm[BS0O + tid] = bih0[tid] + bhh0[tid];
        sm[BS1O + tid] = bih1[tid] + bhh1[tid];
    }
    if (tid < DIM) sm[BFCO + tid] = bfc[tid];
    if (tid < 2 * DIM) { sm[H0O + tid] = 0.0f; sm[H1O + tid] = 0.0f; }
    for (int idx = tid; idx < DIM * DIM; idx += THREADS) {   // W_fc: (k4,c,j)
        const int j = idx >> 6, k = idx & 63;
        sm[WFCO + (k >> 2) * 256 + (k & 3) * 64 + j] = Wfc[idx];
    }

    // ---- recurrent weights in registers: 32 float4 = 128 VGPR (R4-proven) ----
    const float* Ws0 = m ? Whh0 : Wih0;
    const float* Ws1 = m ? Whh1 : Wih1;
    float4 w0a[8], w0b[8], w1a[8], w1b[8];
#pragma unroll
    for (int k4 = 0; k4 < 8; ++k4) {
        w0a[k4] = *reinterpret_cast<const float4*>(Ws0 + g0 * DIM + kh * 32 + k4 * 4);
        w0b[k4] = *reinterpret_cast<const float4*>(Ws0 + g1 * DIM + kh * 32 + k4 * 4);
        w1a[k4] = *reinterpret_cast<const float4*>(Ws1 + g0 * DIM + kh * 32 + k4 * 4);
        w1b[k4] = *reinterpret_cast<const float4*>(Ws1 + g1 * DIM + kh * 32 + k4 * 4);
    }
    __syncthreads();

    const int row0 = bid * ROWS;
    const float* xb = x + (size_t)row0 * TSEQ * DIM + kh * 32;
    const size_t XRS = (size_t)TSEQ * DIM;

    float c_state = 0.0f;   // c0 for tid<128; c1 for tid in [128,256)

    // ========= encoder: cross-layer software pipeline, 2 barriers/step =========
    // iteration s: [L0mv(s) + L1mv(s-1)] | bar | [combine0(s) || combine1(s-1)] | bar
    for (int s = 0; s < TSEQ; ++s) {
        // ---- matvec phase (all threads) ----
        {   // L0mv(s): inputs x_s (m=0) or h0_{s-1} in H0O (m=1)
            float a00 = 0.f, a01 = 0.f, a10 = 0.f, a11 = 0.f;
            if (m == 0) {
                const float* xs = xb + (size_t)s * DIM;
#pragma unroll
                for (int k4 = 0; k4 < 8; ++k4) {
                    const float4 v0 = *reinterpret_cast<const float4*>(xs + 0 * XRS + k4 * 4);
                    const float4 v1 = *reinterpret_cast<const float4*>(xs + 1 * XRS + k4 * 4);
                    fma4v(a00, v0, w0a[k4]); fma4v(a01, v0, w0b[k4]);
                    fma4v(a10, v1, w0a[k4]); fma4v(a11, v1, w0b[k4]);
                }
            } else {
#pragma unroll
                for (int k4 = 0; k4 < 8; ++k4) {
                    const float4 v0 = *reinterpret_cast<const float4*>(sm + H0O + 0 * 64 + kh * 32 + k4 * 4);
                    const float4 v1 = *reinterpret_cast<const float4*>(sm + H0O + 1 * 64 + kh * 32 + k4 * 4);
                    fma4v(a00, v0, w0a[k4]); fma4v(a01, v0, w0b[k4]);
                    fma4v(a10, v1, w0a[k4]); fma4v(a11, v1, w0b[k4]);
                }
            }
            sm[P0O + pb + g0]       = a00; sm[P0O + pb + g1]       = a01;
            sm[P0O + pb + 256 + g0] = a10; sm[P0O + pb + 256 + g1] = a11;
        }
        if (s != 0) {   // L1mv(s-1): inputs h0_{s-1} (m=0, H0O) or h1_{s-2} (m=1, H1O)
            const int ib = m ? H1O : H0O;
            float b00 = 0.f, b01 = 0.f, b10 = 0.f, b11 = 0.f;
#pragma unroll
            for (int k4 = 0; k4 < 8; ++k4) {
                const float4 v0 = *reinterpret_cast<const float4*>(sm + ib + 0 * 64 + kh * 32 + k4 * 4);
                const float4 v1 = *reinterpret_cast<const float4*>(sm + ib + 1 * 64 + kh * 32 + k4 * 4);
                fma4v(b00, v0, w1a[k4]); fma4v(b01, v0, w1b[k4]);
                fma4v(b10, v1, w1a[k4]); fma4v(b11, v1, w1b[k4]);
            }
            sm[P1O + pb + g0]       = b00; sm[P1O + pb + g1]       = b01;
            sm[P1O + pb + 256 + g0] = b10; sm[P1O + pb + 256 + g1] = b11;
        }
        __syncthreads();

        // ---- combine phase: combine0(s) on tid<128 || combine1(s-1) on [128,256) ----
        if (tid < 128) {
            float pi = sm[BS0O + jc],       pf = sm[BS0O + 64 + jc];
            float pg = sm[BS0O + 128 + jc], po = sm[BS0O + 192 + jc];
#pragma unroll
            for (int cp = 0; cp < 4; ++cp) {
                const float* p = sm + P0O + cp * 512 + rc * 256;
                pi += p[jc]; pf += p[64 + jc]; pg += p[128 + jc]; po += p[192 + jc];
            }
            const float ig = sigm(pi), fg = sigm(pf), gg = tanh_(pg), og = sigm(po);
            c_state = fmaf(fg, c_state, ig * gg);
            sm[H0O + tid] = og * tanh_(c_state);
        } else if (tid < 256 && s != 0) {
            float pi = sm[BS1O + jc],       pf = sm[BS1O + 64 + jc];
            float pg = sm[BS1O + 128 + jc], po = sm[BS1O + 192 + jc];
#pragma unroll
            for (int cp = 0; cp < 4; ++cp) {
                const float* p = sm + P1O + cp * 512 + rc * 256;
                pi += p[jc]; pf += p[64 + jc]; pg += p[128 + jc]; po += p[192 + jc];
            }
            const float ig = sigm(pi), fg = sigm(pf), gg = tanh_(pg), og = sigm(po);
            c_state = fmaf(fg, c_state, ig * gg);
            sm[H1O + (tid & 127)] = og * tanh_(c_state);
        }
        __syncthreads();
    }

    // ---- drain the pipeline: L1mv(335) + combine1(335) -> decoder carry ----
    {
        const int ib = m ? H1O : H0O;   // h0_335 / h1_334
        float b00 = 0.f, b01 = 0.f, b10 = 0.f, b11 = 0.f;
#pragma unroll
        for (int k4 = 0; k4 < 8; ++k4) {
            const float4 v0 = *reinterpret_cast<const float4*>(sm + ib + 0 * 64 + kh * 32 + k4 * 4);
            const float4 v1 = *reinterpret_cast<const float4*>(sm + ib + 1 * 64 + kh * 32 + k4 * 4);
            fma4v(b00, v0, w1a[k4]); fma4v(b01, v0, w1b[k4]);
            fma4v(b10, v1, w1a[k4]); fma4v(b11, v1, w1b[k4]);
        }
        sm[P1O + pb + g0]       = b00; sm[P1O + pb + g1]       = b01;
        sm[P1O + pb + 256 + g0] = b10; sm[P1O + pb + 256 + g1] = b11;
    }
    __syncthreads();
    if (tid >= 128 && tid < 256) {
        float pi = sm[BS1O + jc],       pf = sm[BS1O + 64 + jc];
        float pg = sm[BS1O + 128 + jc], po = sm[BS1O + 192 + jc];
#pragma unroll
        for (int cp = 0; cp < 4; ++cp) {
            const float* p = sm + P1O + cp * 512 + rc * 256;
            pi += p[jc]; pf += p[64 + jc]; pg += p[128 + jc]; po += p[192 + jc];
        }
        const float ig = sigm(pi), fg = sigm(pf), gg = tanh_(pg), og = sigm(po);
        c_state = fmaf(fg, c_state, ig * gg);
        sm[DBO + (tid & 127)] = og * tanh_(c_state);
    }
    __syncthreads();

    const float bfc_j = sm[BFCO + jc];

    // ============ decoder: 96 autoregressive steps (zero-state, serial) ============
    for (int p = 0; p < PRED; ++p) {
        // ---- cell0 mv: m==0 groups (copies 0,2) from DBO ----
        if (m == 0) {
            float a00 = 0.f, a01 = 0.f, a10 = 0.f, a11 = 0.f;
#pragma unroll
            for (int k4 = 0; k4 < 8; ++k4) {
                const float4 v0 = *reinterpret_cast<const float4*>(sm + DBO + 0 * 64 + kh * 32 + k4 * 4);
                const float4 v1 = *reinterpret_cast<const float4*>(sm + DBO + 1 * 64 + kh * 32 + k4 * 4);
                fma4v(a00, v0, w0a[k4]); fma4v(a01, v0, w0b[k4]);
                fma4v(a10, v1, w0a[k4]); fma4v(a11, v1, w0b[k4]);
            }
            sm[P0O + pb + g0]       = a00; sm[P0O + pb + g1]       = a01;
            sm[P0O + pb + 256 + g0] = a10; sm[P0O + pb + 256 + g1] = a11;
        }
        __syncthreads();
        if (tid < 128) {   // combine0 zero-state: c=i*g (copies 0,2)
            float pi = sm[BS0O + jc], pg = sm[BS0O + 128 + jc], po = sm[BS0O + 192 + jc];
            const float* pA = sm + P0O + 0 * 512 + rc * 256;
            const float* pB = sm + P0O + 2 * 512 + rc * 256;
            pi += pA[jc] + pB[jc];
            pg += pA[128 + jc] + pB[128 + jc];
            po += pA[192 + jc] + pB[192 + jc];
            const float ig = sigm(pi), gg = tanh_(pg), og = sigm(po);
            sm[H0O + tid] = og * tanh_(ig * gg);
        }
        __syncthreads();

        // ---- cell1 mv: m==0 groups from H0 ----
        if (m == 0) {
            float b00 = 0.f, b01 = 0.f, b10 = 0.f, b11 = 0.f;
#pragma unroll
            for (int k4 = 0; k4 < 8; ++k4) {
                const float4 v0 = *reinterpret_cast<const float4*>(sm + H0O + 0 * 64 + kh * 32 + k4 * 4);
                const float4 v1 = *reinterpret_cast<const float4*>(sm + H0O + 1 * 64 + kh * 32 + k4 * 4);
                fma4v(b00, v0, w1a[k4]); fma4v(b01, v0, w1b[k4]);
                fma4v(b10, v1, w1a[k4]); fma4v(b11, v1, w1b[k4]);
            }
            sm[P1O + pb + g0]       = b00; sm[P1O + pb + g1]       = b01;
            sm[P1O + pb + 256 + g0] = b10; sm[P1O + pb + 256 + g1] = b11;
        }
        __syncthreads();
        if (tid >= 128 && tid < 256) {  // combine1 zero-state (copies 0,2)
            float pi = sm[BS1O + jc], pg = sm[BS1O + 128 + jc], po = sm[BS1O + 192 + jc];
            const float* pA = sm + P1O + 0 * 512 + rc * 256;
            const float* pB = sm + P1O + 2 * 512 + rc * 256;
            pi += pA[jc] + pB[jc];
            pg += pA[128 + jc] + pB[128 + jc];
            po += pA[192 + jc] + pB[192 + jc];
            const float ig = sigm(pi), gg = tanh_(pg), og = sigm(po);
            sm[H1O + (tid & 127)] = og * tanh_(ig * gg);
        }
        __syncthreads();

        // ---- FC (tid<128): uniform h1 b128 + stride-1 b32 W_fc ----
        if (tid < 128) {
            float acc = bfc_j;
            const float4* hp = reinterpret_cast<const float4*>(sm + H1O + rc * 64);
#pragma unroll
            for (int k4 = 0; k4 < 16; ++k4) {
                const float4 hv = hp[k4];
                const float* wp = sm + WFCO + k4 * 256;
                acc = fmaf(hv.x, wp[jc],       acc);
                acc = fmaf(hv.y, wp[64 + jc],  acc);
                acc = fmaf(hv.z, wp[128 + jc], acc);
                acc = fmaf(hv.w, wp[192 + jc], acc);
            }
            out[(size_t)(row0 + rc) * PRED * DIM + p * DIM + jc] = acc;
            sm[DBO + tid] = acc;
        }
        __syncthreads();
    }
}

extern "C" void kernel_launch(void* const* d_in, const int* in_sizes, int n_in,
                              void* d_out, int out_size, void* d_ws, size_t ws_size,
                              hipStream_t stream) {
    const float* x    = (const float*)d_in[0];
    const float* Wih0 = (const float*)d_in[1];
    const float* Whh0 = (const float*)d_in[2];
    const float* bih0 = (const float*)d_in[3];
    const float* bhh0 = (const float*)d_in[4];
    const float* Wih1 = (const float*)d_in[5];
    const float* Whh1 = (const float*)d_in[6];
    const float* bih1 = (const float*)d_in[7];
    const float* bhh1 = (const float*)d_in[8];
    const float* Wfc  = (const float*)d_in[9];
    const float* bfc  = (const float*)d_in[10];
    float* out = (float*)d_out;

    hipLaunchKernelGGL(rnn_fused, dim3(NB / ROWS), dim3(THREADS), SMEM_BYTES, stream,
                       x, Wih0, Whh0, bih0, bhh0, Wih1, Whh1, bih1, bhh1, Wfc, bfc, out);
}